// Round 1
// baseline (382.782 us; speedup 1.0000x reference)
//
#include <hip/hip_runtime.h>

// Problem: B=262144, n_in=128, n_middle=512, n_extra=2
// out[b][c] = x[b][c] + o[c]
//   xbar[0:128] = (sum_b w_b * x_b) / sum_b w_b ; xbar[128:130] = p
//   h = relu(W_in @ xbar)  [512]
//   o = W_out @ h          [128]
//
// ws layout (floats):
//   [0..127]   acc (sum_b w_b * x_b)   -- atomically accumulated
//   [128]      wsum                     -- atomically accumulated
//   [132..259] o (16B-aligned: 132*4 = 528 bytes)

__device__ __forceinline__ float4 f4add(float4 a, float4 b) {
    return make_float4(a.x + b.x, a.y + b.y, a.z + b.z, a.w + b.w);
}

// Kernel 1: weighted reduction over rows.
// 256 threads: tid = rowg*32 + colv ; colv indexes the 32 float4s of a row,
// rowg in [0,8) picks one of 8 rows processed per iteration (coalesced:
// 32 consecutive lanes read 512 contiguous bytes of one row).
__global__ void wreduce_kernel(const float* __restrict__ x,
                               const float* __restrict__ w,
                               float* __restrict__ acc,   // 129 floats
                               int B) {
    __shared__ float4 smem[256];
    __shared__ float wsh[8];
    const int tid  = threadIdx.x;
    const int colv = tid & 31;
    const int rowg = tid >> 5;
    const float4* __restrict__ x4 = (const float4*)x;

    float4 a = make_float4(0.f, 0.f, 0.f, 0.f);
    float wloc = 0.f;
    const int groups = B >> 3;             // groups of 8 rows
    for (int g = blockIdx.x; g < groups; g += gridDim.x) {
        const int row = (g << 3) + rowg;
        const float wv = w[row];           // broadcast across 32 lanes
        const float4 xv = x4[row * 32 + colv];
        a.x += wv * xv.x; a.y += wv * xv.y;
        a.z += wv * xv.z; a.w += wv * xv.w;
        wloc += wv;
    }
    smem[tid] = a;
    if (colv == 0) wsh[rowg] = wloc;
    __syncthreads();
    // reduce the 8 row-groups down to 1 (tid layout preserves colv)
    if (tid < 128) smem[tid] = f4add(smem[tid], smem[tid + 128]);
    __syncthreads();
    if (tid < 64)  smem[tid] = f4add(smem[tid], smem[tid + 64]);
    __syncthreads();
    if (tid < 32) {
        float4 r = f4add(smem[tid], smem[tid + 32]);
        atomicAdd(&acc[tid * 4 + 0], r.x);
        atomicAdd(&acc[tid * 4 + 1], r.y);
        atomicAdd(&acc[tid * 4 + 2], r.z);
        atomicAdd(&acc[tid * 4 + 3], r.w);
    }
    if (tid == 0) {
        float ws = 0.f;
        #pragma unroll
        for (int i = 0; i < 8; i++) ws += wsh[i];
        atomicAdd(&acc[128], ws);
    }
}

// Kernel 2: single block, 512 threads. xbar -> h=relu(W_in@xbar) -> o=W_out@h.
__global__ void matvec_kernel(const float* __restrict__ acc,   // 129 floats
                              const float* __restrict__ p,     // 2 floats
                              const float* __restrict__ W_in,  // [512,130]
                              const float* __restrict__ W_out, // [128,512]
                              float* __restrict__ o_out) {     // 128 floats
    __shared__ float xbar[130];
    __shared__ float h[512];
    const int tid = threadIdx.x;
    const float inv = 1.0f / acc[128];
    if (tid < 128) xbar[tid] = acc[tid] * inv;
    else if (tid < 130) xbar[tid] = p[tid - 128];
    __syncthreads();
    {
        const float* __restrict__ row = W_in + tid * 130;
        float s = 0.f;
        #pragma unroll 10
        for (int k = 0; k < 130; k++) s += row[k] * xbar[k];
        h[tid] = fmaxf(s, 0.f);
    }
    __syncthreads();
    if (tid < 128) {
        const float* __restrict__ row = W_out + tid * 512;
        float s = 0.f;
        #pragma unroll 8
        for (int k = 0; k < 512; k++) s += row[k] * h[k];
        o_out[tid] = s;
    }
}

// Kernel 3: out = x + o (broadcast over rows), float4 grid-stride.
__global__ void bcast_add_kernel(const float* __restrict__ x,
                                 const float* __restrict__ o,
                                 float* __restrict__ out,
                                 int n4) {
    const float4* __restrict__ x4 = (const float4*)x;
    const float4* __restrict__ o4 = (const float4*)o;
    float4* __restrict__ out4 = (float4*)out;
    const int stride = gridDim.x * blockDim.x;
    for (int i = blockIdx.x * blockDim.x + threadIdx.x; i < n4; i += stride) {
        const float4 xv = x4[i];
        const float4 ov = o4[i & 31];      // 32 float4s per 128-float row
        out4[i] = make_float4(xv.x + ov.x, xv.y + ov.y,
                              xv.z + ov.z, xv.w + ov.w);
    }
}

extern "C" void kernel_launch(void* const* d_in, const int* in_sizes, int n_in,
                              void* d_out, int out_size, void* d_ws, size_t ws_size,
                              hipStream_t stream) {
    const float* x     = (const float*)d_in[0];
    const float* w     = (const float*)d_in[1];
    const float* p     = (const float*)d_in[2];
    const float* W_in  = (const float*)d_in[3];
    const float* W_out = (const float*)d_in[4];
    float* out = (float*)d_out;
    float* ws  = (float*)d_ws;

    const int B = in_sizes[1];             // 262144
    float* acc   = ws;                     // 129 floats
    float* o_vec = ws + 132;               // 128 floats, 16B-aligned

    // zero the accumulators (ws is poisoned 0xAA before every call)
    hipMemsetAsync(acc, 0, 129 * sizeof(float), stream);

    wreduce_kernel<<<1024, 256, 0, stream>>>(x, w, acc, B);
    matvec_kernel<<<1, 512, 0, stream>>>(acc, p, W_in, W_out, o_vec);

    const int n4 = B * 32;                 // B*128/4 float4 elements
    bcast_add_kernel<<<8192, 256, 0, stream>>>(x, o_vec, out, n4);
}

// Round 2
// 377.424 us; speedup vs baseline: 1.0142x; 1.0142x over previous
//
#include <hip/hip_runtime.h>

// B=262144, n_in=128, n_middle=512, n_extra=2
// Collapsed math:
//   acc[0:128] = sum_b w_b * x_b ; acc[128] = sum_b w_b
//   xbar = [acc/acc[128], p] ; h = relu(W_in @ xbar) ; o = W_out @ h
//   out = x + o (broadcast over rows)
//
// ws floats: [0..128] acc (atomic), [132..259] o (16B aligned)

__device__ __forceinline__ float4 f4add(float4 a, float4 b) {
    return make_float4(a.x + b.x, a.y + b.y, a.z + b.z, a.w + b.w);
}

// Kernel 1: weighted reduction. Flat float4 indexing; column of float4 i is
// (i & 31), invariant per thread since stride % 32 == 0. 4-way unroll with
// independent accumulators -> 4 float4 loads in flight per thread.
__global__ __launch_bounds__(256) void wreduce_kernel(
        const float4* __restrict__ x4, const float* __restrict__ w,
        float* __restrict__ acc, int n4) {
    __shared__ float4 smem[256];
    __shared__ float wsh[8];
    const int tid  = threadIdx.x;
    const int colv = tid & 31;
    const float is0 = (colv == 0) ? 1.0f : 0.0f;  // w counted once per row
    const int stride = gridDim.x * blockDim.x;

    float4 a0 = make_float4(0,0,0,0), a1 = a0, a2 = a0, a3 = a0;
    float wl0 = 0.f, wl1 = 0.f, wl2 = 0.f, wl3 = 0.f;

    int i = blockIdx.x * blockDim.x + tid;
    for (; i + 3 * stride < n4; i += 4 * stride) {
        const int i0 = i, i1 = i + stride, i2 = i + 2 * stride, i3 = i + 3 * stride;
        const float4 v0 = x4[i0], v1 = x4[i1], v2 = x4[i2], v3 = x4[i3];
        const float w0 = w[i0 >> 5], w1 = w[i1 >> 5], w2 = w[i2 >> 5], w3 = w[i3 >> 5];
        a0.x += w0*v0.x; a0.y += w0*v0.y; a0.z += w0*v0.z; a0.w += w0*v0.w;
        a1.x += w1*v1.x; a1.y += w1*v1.y; a1.z += w1*v1.z; a1.w += w1*v1.w;
        a2.x += w2*v2.x; a2.y += w2*v2.y; a2.z += w2*v2.z; a2.w += w2*v2.w;
        a3.x += w3*v3.x; a3.y += w3*v3.y; a3.z += w3*v3.z; a3.w += w3*v3.w;
        wl0 += is0 * w0; wl1 += is0 * w1; wl2 += is0 * w2; wl3 += is0 * w3;
    }
    for (; i < n4; i += stride) {  // tail (empty at these sizes)
        const float4 v0 = x4[i];
        const float w0 = w[i >> 5];
        a0.x += w0*v0.x; a0.y += w0*v0.y; a0.z += w0*v0.z; a0.w += w0*v0.w;
        wl0 += is0 * w0;
    }

    float4 a = f4add(f4add(a0, a1), f4add(a2, a3));
    smem[tid] = a;
    if (colv == 0) wsh[tid >> 5] = wl0 + wl1 + wl2 + wl3;
    __syncthreads();
    if (tid < 128) smem[tid] = f4add(smem[tid], smem[tid + 128]);
    __syncthreads();
    if (tid < 64)  smem[tid] = f4add(smem[tid], smem[tid + 64]);
    __syncthreads();
    if (tid < 32) {
        float4 r = f4add(smem[tid], smem[tid + 32]);
        atomicAdd(&acc[tid * 4 + 0], r.x);
        atomicAdd(&acc[tid * 4 + 1], r.y);
        atomicAdd(&acc[tid * 4 + 2], r.z);
        atomicAdd(&acc[tid * 4 + 3], r.w);
    }
    if (tid == 0) {
        float ws = 0.f;
        #pragma unroll
        for (int k = 0; k < 8; k++) ws += wsh[k];
        atomicAdd(&acc[128], ws);
    }
}

// Kernel 2: single block, 1024 threads. xbar -> h -> o with vector loads and
// shuffle-combined partial dots (2 thr/h-row over float2, 8 thr/o-row over float4).
__global__ __launch_bounds__(1024) void matvec_kernel(
        const float* __restrict__ acc, const float* __restrict__ p,
        const float* __restrict__ W_in, const float* __restrict__ W_out,
        float* __restrict__ o_out) {
    __shared__ float xbar[130];
    __shared__ float h[512];
    const int t = threadIdx.x;
    const float inv = 1.0f / acc[128];
    if (t < 128) xbar[t] = acc[t] * inv;
    else if (t < 130) xbar[t] = p[t - 128];
    __syncthreads();
    {
        const int r = t >> 1, half = t & 1;           // 2 threads per row of W_in
        const float2* __restrict__ row2 = (const float2*)(W_in + r * 130);
        const int j0 = half ? 33 : 0, j1 = half ? 65 : 33;
        float s = 0.f;
        #pragma unroll 11
        for (int j = j0; j < j1; ++j) {
            const float2 wv = row2[j];
            s += wv.x * xbar[2 * j] + wv.y * xbar[2 * j + 1];
        }
        s += __shfl_down(s, 1, 2);
        if (half == 0) h[r] = fmaxf(s, 0.f);
    }
    __syncthreads();
    {
        const int r = t >> 3, seg = t & 7;            // 8 threads per row of W_out
        const float4* __restrict__ row4 = (const float4*)(W_out + r * 512) + seg * 16;
        const float* __restrict__ hseg = h + seg * 64;
        float s = 0.f;
        #pragma unroll
        for (int j = 0; j < 16; ++j) {
            const float4 wv = row4[j];
            s += wv.x * hseg[4*j] + wv.y * hseg[4*j+1] + wv.z * hseg[4*j+2] + wv.w * hseg[4*j+3];
        }
        #pragma unroll
        for (int off = 4; off; off >>= 1) s += __shfl_down(s, off, 8);
        if (seg == 0) o_out[r] = s;
    }
}

// Kernel 3: out = x + o. Per-thread column is grid-stride-invariant, so o is
// loaded ONCE into registers; 4-way unrolled streaming add.
__global__ __launch_bounds__(256) void bcast_add_kernel(
        const float4* __restrict__ x4, const float4* __restrict__ o4,
        float4* __restrict__ out4, int n4) {
    const int stride = gridDim.x * blockDim.x;
    int i = blockIdx.x * blockDim.x + threadIdx.x;
    const float4 ov = o4[i & 31];        // constant: stride % 32 == 0
    for (; i + 3 * stride < n4; i += 4 * stride) {
        const int i0 = i, i1 = i + stride, i2 = i + 2 * stride, i3 = i + 3 * stride;
        const float4 v0 = x4[i0], v1 = x4[i1], v2 = x4[i2], v3 = x4[i3];
        out4[i0] = f4add(v0, ov);
        out4[i1] = f4add(v1, ov);
        out4[i2] = f4add(v2, ov);
        out4[i3] = f4add(v3, ov);
    }
    for (; i < n4; i += stride) out4[i] = f4add(x4[i], ov);
}

extern "C" void kernel_launch(void* const* d_in, const int* in_sizes, int n_in,
                              void* d_out, int out_size, void* d_ws, size_t ws_size,
                              hipStream_t stream) {
    const float* x     = (const float*)d_in[0];
    const float* w     = (const float*)d_in[1];
    const float* p     = (const float*)d_in[2];
    const float* W_in  = (const float*)d_in[3];
    const float* W_out = (const float*)d_in[4];
    float* out = (float*)d_out;
    float* ws  = (float*)d_ws;

    float* acc   = ws;          // 129 floats
    float* o_vec = ws + 132;    // 128 floats, 16B aligned

    const int n4 = in_sizes[0] / 4;   // 8388608 float4s of x

    hipMemsetAsync(acc, 0, 129 * sizeof(float), stream);
    wreduce_kernel<<<1024, 256, 0, stream>>>((const float4*)x, w, acc, n4);
    matvec_kernel<<<1, 1024, 0, stream>>>(acc, p, W_in, W_out, o_vec);
    bcast_add_kernel<<<2048, 256, 0, stream>>>((const float4*)x, (const float4*)o_vec,
                                               (float4*)out, n4);
}

// Round 4
// 259.349 us; speedup vs baseline: 1.4759x; 1.4553x over previous
//
#include <hip/hip_runtime.h>

// B=262144, n_in=128, n_middle=512, n_extra=2
// Collapsed math:
//   acc[0:128] = sum_b w_b * x_b ; wsum = sum_b w_b
//   xbar = [acc/wsum, p] ; h = relu(W_in @ xbar) ; o = W_out @ h
//   out = x + o (broadcast over rows)
//
// ws layout (floats):
//   [0          .. 262143]  p4T : per-block partials, TRANSPOSED [col4][block]
//                            (NBLK=2048 blocks x 32 float4 cols, 1 MiB)
//   [262144     .. 264191]  pw  : per-block wsum partials (2048)
//   [264192     .. 264319]  acc : reduced weighted sum (128)
//   [264320]                wsum
//   [264384     .. 264895]  h (512)
//   [264896     .. 265023]  o (128)

#define NBLK_A 2048
#define OFF_PW   262144
#define OFF_ACC  264192
#define OFF_WSUM 264320
#define OFF_H    264384
#define OFF_O    264896

typedef float f4raw __attribute__((ext_vector_type(4)));  // nontemporal-compatible

__device__ __forceinline__ float4 f4add(float4 a, float4 b) {
    return make_float4(a.x + b.x, a.y + b.y, a.z + b.z, a.w + b.w);
}

// ---- Stage A: per-block weighted partial sums. Simple 1-load/iter grid-stride
// (m13-copy style), 2048 blocks -> full occupancy; NO atomics.
__global__ __launch_bounds__(256) void wreduce_stageA(
        const float4* __restrict__ x4, const float* __restrict__ w,
        float4* __restrict__ p4T, float* __restrict__ pw, int n4) {
    __shared__ float4 smem[256];
    __shared__ float wsh[8];
    const int tid  = threadIdx.x;
    const int colv = tid & 31;                 // i % 32 == colv (stride % 32 == 0)
    const float is0 = (colv == 0) ? 1.0f : 0.0f;
    const int stride = gridDim.x * blockDim.x;

    float4 a = make_float4(0.f, 0.f, 0.f, 0.f);
    float wl = 0.f;
    for (int i = blockIdx.x * blockDim.x + tid; i < n4; i += stride) {
        const float4 v = x4[i];
        const float wv = w[i >> 5];
        a.x += wv * v.x; a.y += wv * v.y; a.z += wv * v.z; a.w += wv * v.w;
        wl += is0 * wv;
    }
    smem[tid] = a;
    if (colv == 0) wsh[tid >> 5] = wl;
    __syncthreads();
    if (tid < 128) smem[tid] = f4add(smem[tid], smem[tid + 128]);
    __syncthreads();
    if (tid < 64)  smem[tid] = f4add(smem[tid], smem[tid + 64]);
    __syncthreads();
    if (tid < 32) {
        float4 r = f4add(smem[tid], smem[tid + 32]);
        p4T[tid * NBLK_A + blockIdx.x] = r;    // transposed for coalesced stage B
    }
    if (tid == 0) {
        float s = 0.f;
        #pragma unroll
        for (int k = 0; k < 8; k++) s += wsh[k];
        pw[blockIdx.x] = s;
    }
}

// ---- Stage B: 33 blocks. Blocks 0..31 reduce one float4 column over 2048
// partials (coalesced); block 32 reduces the 2048 wsum partials.
__global__ __launch_bounds__(256) void wreduce_stageB(
        const float4* __restrict__ p4T, const float* __restrict__ pw,
        float4* __restrict__ acc4, float* __restrict__ wsum) {
    __shared__ float4 smem[256];
    const int t = threadIdx.x, b = blockIdx.x;
    if (b < 32) {
        const float4* __restrict__ col = p4T + b * NBLK_A;
        float4 a = make_float4(0.f, 0.f, 0.f, 0.f);
        #pragma unroll
        for (int k = 0; k < NBLK_A / 256; k++) a = f4add(a, col[t + k * 256]);
        smem[t] = a;
        __syncthreads();
        for (int off = 128; off > 0; off >>= 1) {
            if (t < off) smem[t] = f4add(smem[t], smem[t + off]);
            __syncthreads();
        }
        if (t == 0) acc4[b] = smem[0];
    } else {
        float s = 0.f;
        #pragma unroll
        for (int k = 0; k < NBLK_A / 256; k++) s += pw[t + k * 256];
        ((float*)smem)[t] = s;
        __syncthreads();
        for (int off = 128; off > 0; off >>= 1) {
            if (t < off) ((float*)smem)[t] += ((float*)smem)[t + off];
            __syncthreads();
        }
        if (t == 0) *wsum = ((float*)smem)[0];
    }
}

// ---- h = relu(W_in @ [acc/wsum, p]) : one wave per row (512 rows).
// Lane l covers k = 2l,2l+1 via float2; lane 0 adds the p-part (k=128,129).
__global__ __launch_bounds__(512) void h_kernel(
        const float* __restrict__ acc, const float* __restrict__ wsum_p,
        const float* __restrict__ p, const float* __restrict__ W_in,
        float* __restrict__ h) {
    const int lane = threadIdx.x & 63;
    const int r = blockIdx.x * 8 + (threadIdx.x >> 6);
    const float inv = 1.0f / *wsum_p;
    const float2* __restrict__ row2 = (const float2*)(W_in + r * 130);
    const float2 wv = row2[lane];
    const float2 av = ((const float2*)acc)[lane];
    float s = wv.x * av.x + wv.y * av.y;
    #pragma unroll
    for (int off = 32; off; off >>= 1) s += __shfl_xor(s, off);
    if (lane == 0) {
        const float2 wp = row2[64];
        const float sp = wp.x * p[0] + wp.y * p[1];
        h[r] = fmaxf(inv * s + sp, 0.f);
    }
}

// ---- o = W_out @ h : one wave per row (128 rows); lane l covers float4
// chunks l and l+64 of the 512-wide dot.
__global__ __launch_bounds__(512) void o_kernel(
        const float* __restrict__ h, const float* __restrict__ W_out,
        float* __restrict__ o) {
    const int lane = threadIdx.x & 63;
    const int r = blockIdx.x * 8 + (threadIdx.x >> 6);
    const float4* __restrict__ row4 = (const float4*)(W_out + r * 512);
    const float4* __restrict__ h4 = (const float4*)h;
    const float4 wa = row4[lane],      wb = row4[lane + 64];
    const float4 ha = h4[lane],        hb = h4[lane + 64];
    float s = wa.x*ha.x + wa.y*ha.y + wa.z*ha.z + wa.w*ha.w
            + wb.x*hb.x + wb.y*hb.y + wb.z*hb.z + wb.w*hb.w;
    #pragma unroll
    for (int off = 32; off; off >>= 1) s += __shfl_xor(s, off);
    if (lane == 0) o[r] = s;
}

// ---- out = x + o : minimal copy-style kernel, nontemporal stores.
__global__ __launch_bounds__(256) void bcast_add_kernel(
        const float4* __restrict__ x4, const float4* __restrict__ o4,
        f4raw* __restrict__ out4, int n4) {
    int i = blockIdx.x * blockDim.x + threadIdx.x;
    const float4 ov = o4[i & 31];              // column invariant: stride % 32 == 0
    const int stride = gridDim.x * blockDim.x;
    for (; i < n4; i += stride) {
        const float4 v = x4[i];
        f4raw r = {v.x + ov.x, v.y + ov.y, v.z + ov.z, v.w + ov.w};
        __builtin_nontemporal_store(r, &out4[i]);
    }
}

extern "C" void kernel_launch(void* const* d_in, const int* in_sizes, int n_in,
                              void* d_out, int out_size, void* d_ws, size_t ws_size,
                              hipStream_t stream) {
    const float* x     = (const float*)d_in[0];
    const float* w     = (const float*)d_in[1];
    const float* p     = (const float*)d_in[2];
    const float* W_in  = (const float*)d_in[3];
    const float* W_out = (const float*)d_in[4];
    float* out = (float*)d_out;
    float* ws  = (float*)d_ws;

    float4* p4T  = (float4*)ws;
    float*  pw   = ws + OFF_PW;
    float*  acc  = ws + OFF_ACC;
    float*  wsum = ws + OFF_WSUM;
    float*  h    = ws + OFF_H;
    float*  o    = ws + OFF_O;

    const int n4 = in_sizes[0] / 4;            // 8,388,608 float4s of x

    wreduce_stageA<<<NBLK_A, 256, 0, stream>>>((const float4*)x, w, p4T, pw, n4);
    wreduce_stageB<<<33, 256, 0, stream>>>(p4T, pw, (float4*)acc, wsum);
    h_kernel<<<64, 512, 0, stream>>>(acc, wsum, p, W_in, h);
    o_kernel<<<16, 512, 0, stream>>>(h, W_out, o);
    bcast_add_kernel<<<8192, 256, 0, stream>>>((const float4*)x, (const float4*)o,
                                               (f4raw*)out, n4);
}